// Round 20
// baseline (63.367 us; speedup 1.0000x reference)
//
#include <hip/hip_runtime.h>

#define IN 128
#define PD 64
#define C1 64
#define C2 128
#define ICC 12
#define NOBJ 32
#define PADW 66    // 64 + 1 halo each side (conv2 input)

typedef __attribute__((ext_vector_type(8))) short bf16x8;
typedef __attribute__((ext_vector_type(4))) float f32x4;

static __device__ __forceinline__ unsigned short f2bf(float f) {
  unsigned u = __float_as_uint(f);
  return (unsigned short)((u + 0x7FFFu + ((u >> 16) & 1u)) >> 16);  // RNE
}

// ---------------------------------------------------------------------------
// K0b: pack w1 (64,12,3,3) f32 -> wp1[tap(10)][oc(64)][ch(16)] bf16 (20 KB).
// ---------------------------------------------------------------------------
__global__ __launch_bounds__(256) void k0_pack_w1(
    const float* __restrict__ w1, unsigned short* __restrict__ wp)
{
  int i = blockIdx.x * 256 + threadIdx.x;
  if (i < 10 * C1 * 16) {
    int tap = i >> 10;
    int rem = i & 1023;
    int oc = rem >> 4, ch = rem & 15;
    float v = (tap < 9 && ch < ICC) ? w1[((size_t)oc * ICC + ch) * 9 + tap] : 0.f;
    wp[i] = f2bf(v);
  }
}

// ---------------------------------------------------------------------------
// K1: exact R15 version (best measured; k1 ~ 23-26 us).
// ---------------------------------------------------------------------------
__global__ __launch_bounds__(512, 4) void k1_mfma(
    const float* __restrict__ img, const unsigned short* __restrict__ wp1,
    const float* __restrict__ b1, const float* __restrict__ w2,
    unsigned short* __restrict__ wq, unsigned short* __restrict__ xpad)
{
  const int t = threadIdx.x;

  if (blockIdx.y == 32) {
    for (int j = blockIdx.x * 512 + t; j < 9 * C2 * C1; j += 64 * 512) {
      const int tmp = j / 9, tap = j - tmp * 9;   // j = (oc*64+ic)*9 + tap
      const int ic = tmp & 63, oc = tmp >> 6;
      const int k2 = ic >> 5, l16 = (ic >> 3) & 3, e = ic & 7;
      const int ocb = oc >> 4, l15 = oc & 15;
      wq[((tap * 2 + k2) * 8 + ocb) * 512 + l16 * 128 + l15 * 8 + e] = f2bf(w2[j]);
    }
    return;
  }

  const int l = t & 63, w = t >> 6;
  const int wm = w >> 1, wn = w & 1;          // 4M x 2N
  const int bx = blockIdx.x & 7, by = blockIdx.x >> 3;
  const int b  = blockIdx.y;
  const int l15 = l & 15, l16 = l >> 4;

  __shared__ uint4 xs4[324 * 3];              // 324 pix x 48B = 15552 B (pad)

  if (t < 324) {
    unsigned int* xu = reinterpret_cast<unsigned int*>(xs4);
    xu[t * 12 + 6] = 0;
    xu[t * 12 + 7] = 0;
  }

  const float* imgb = img + ((size_t)b * ICC << 14);
  float v0[4], v1[4];
  int   dpix[4], dcp[4];
#pragma unroll
  for (int it = 0; it < 4; ++it) {
    const int i = t + it * 512;               // < 1944 = 324 px * 6 cp
    const bool ok = i < 1944;
    const int cp  = ok ? (i / 324) : 0;
    const int pix = i - cp * 324;
    const int y = (pix * 57) >> 10;           // pix / 18
    const int x = pix - y * 18;
    const int iy = by * 16 + y - 1, ix = bx * 16 + x - 1;
    dpix[it] = pix; dcp[it] = cp;
    v0[it] = 0.f; v1[it] = 0.f;
    if (ok && iy >= 0 && iy < IN && ix >= 0 && ix < IN) {
      const float* p0 = imgb + ((size_t)(2 * cp) << 14) + iy * IN + ix;
      v0[it] = p0[0];
      v1[it] = p0[16384];
    }
  }
#pragma unroll
  for (int it = 0; it < 4; ++it) {
    if (t + it * 512 < 1944) {
      unsigned short h0 = f2bf(v0[it] * (1.f / 255.f));
      unsigned short h1 = f2bf(v1[it] * (1.f / 255.f));
      reinterpret_cast<unsigned int*>(xs4)[dpix[it] * 12 + dcp[it]] =
          (unsigned int)h0 | ((unsigned int)h1 << 16);
    }
  }
  __syncthreads();

  f32x4 acc[4][2];
#pragma unroll
  for (int mf = 0; mf < 4; ++mf)
#pragma unroll
    for (int nf = 0; nf < 2; ++nf) acc[mf][nf] = (f32x4){0.f, 0.f, 0.f, 0.f};

  const char* xs_raw = reinterpret_cast<const char*>(xs4);
  const int ck = l16 & 1;
#pragma unroll
  for (int kp = 0; kp < 5; ++kp) {
    const int ta = 2 * kp, tb = 2 * kp + 1;   // tb == 9 on last step (zero W)
    const int tbA = (tb > 8) ? 8 : tb;
    const int dya = ta / 3, dxa = ta % 3;
    const int dyb = tbA / 3, dxb = tbA % 3;
    const int dy = (l16 < 2) ? dya : dyb;
    const int dx = (l16 < 2) ? dxa : dxb;
    const int tw = (l16 < 2) ? ta : tb;       // tap 9 -> zeros in wp1

    bf16x8 a[4], bw[2];
#pragma unroll
    for (int mf = 0; mf < 4; ++mf) {
      const int row = wm * 4 + mf;
      const int s = (row + dy) * 18 + (l15 + dx);
      a[mf] = *reinterpret_cast<const bf16x8*>(xs_raw + s * 48 + ck * 16);
    }
#pragma unroll
    for (int nf = 0; nf < 2; ++nf) {
      const int oc = wn * 32 + nf * 16 + l15;
      bw[nf] = *reinterpret_cast<const bf16x8*>(wp1 + ((tw * C1 + oc) * 16 + ck * 8));
    }
#pragma unroll
    for (int mf = 0; mf < 4; ++mf)
#pragma unroll
      for (int nf = 0; nf < 2; ++nf)
        acc[mf][nf] = __builtin_amdgcn_mfma_f32_16x16x32_bf16(
            a[mf], bw[nf], acc[mf][nf], 0, 0, 0);
  }

  float bias[2];
#pragma unroll
  for (int nf = 0; nf < 2; ++nf) bias[nf] = b1[wn * 32 + nf * 16 + l15];

#pragma unroll
  for (int q = 0; q < 2; ++q) {
    const int gy = by * 8 + wm * 2 + q;       // pooled row
    unsigned short* orow = xpad + (((size_t)b * PADW + (gy + 1)) * PADW + 1) * C1;
#pragma unroll
    for (int nf = 0; nf < 2; ++nf) {
      const int oc = wn * 32 + nf * 16 + l15;
      const f32x4 A0 = acc[2 * q][nf], A1 = acc[2 * q + 1][nf];
      const float p0 = fmaxf(fmaxf(A0[0], A0[1]), fmaxf(A1[0], A1[1]));
      const float p1 = fmaxf(fmaxf(A0[2], A0[3]), fmaxf(A1[2], A1[3]));
      const float v0s = fmaxf(p0 + bias[nf], 0.f);
      const float v1s = fmaxf(p1 + bias[nf], 0.f);
      const int gx0 = bx * 8 + l16 * 2;
      orow[(size_t)gx0 * C1 + oc]       = f2bf(v0s);
      orow[(size_t)(gx0 + 1) * C1 + oc] = f2bf(v1s);
    }
  }
}

// ---------------------------------------------------------------------------
// K2 v5: conv2 implicit GEMM, wave tile 128px x 64oc (acc[8][4]): ds_read
// per MFMA halved (8 reads : 32 MFMA vs 8:16) -> total LDS reads 590K->295K
// (was ~11.5us, the dominant k2 term), wq L2 traffic halved. Block = 4 waves
// (2M x 2N) = 16x16 px x 128 oc; 512 blocks; LDS 59.4 KB -> 2 blocks/CU.
// No explicit load pipelining (R7: neutral) -> VGPR ~176+addr, no spill.
// ---------------------------------------------------------------------------
__global__ __launch_bounds__(256) void k2_mfma(
    const unsigned short* __restrict__ xpad, const unsigned short* __restrict__ wq,
    const float* __restrict__ b2, const int* __restrict__ rois,
    float* __restrict__ part)
{
  const int t  = threadIdx.x;
  const int l  = t & 63, w = t >> 6;
  const int wm = w >> 1, wn = w & 1;
  const int bx = blockIdx.x & 3, by = blockIdx.x >> 2;   // 4 x 4 tiles of 16x16
  const int b  = blockIdx.y;
  const int l15 = l & 15, l16 = l >> 4;

  __shared__ uint4 xs4[324 * 8];          // 18x18 pixels x 128B = 41.5 KB
  __shared__ int   smax[NOBJ * 132];      // padded rows of 132 (33 uint4)
  __shared__ int   ids_s[256];

  // ---- stage 18x18 px tile (swizzled source column; border -> zero) ----
  const unsigned short* xb = xpad + (size_t)b * PADW * PADW * C1;
#pragma unroll
  for (int it = 0; it < 11; ++it) {
    const int i = t + it * 256;           // < 2592
    if (i < 2592) {
      const int r = i >> 3, ps = i & 7;
      const int y = (r * 57) >> 10;       // r / 18
      const int x = r - y * 18;
      const int cl = ps ^ (r & 7);
      const int gy = by * 16 + y, gx = bx * 16 + x;
      uint4 v = make_uint4(0, 0, 0, 0);
      if (gy >= 1 && gy <= PD && gx >= 1 && gx <= PD)
        v = *(reinterpret_cast<const uint4*>(xb + ((size_t)gy * PADW + gx) * C1) + cl);
      xs4[i] = v;
    }
  }
  {
    const int py = t >> 4, pxx = t & 15;
    ids_s[t] = rois[((size_t)b * IN + 2 * (by * 16 + py)) * IN + 2 * (bx * 16 + pxx)];
  }
  {
    uint4* sm4 = reinterpret_cast<uint4*>(smax);
    const uint4 z = make_uint4(0, 0, 0, 0);
#pragma unroll
    for (int i = 0; i < 5; ++i) {
      const int j = t + i * 256;
      if (j < 1056) sm4[j] = z;           // 32*132/4 = 1056
    }
  }
  __syncthreads();

  f32x4 acc[8][4];
#pragma unroll
  for (int mf = 0; mf < 8; ++mf)
#pragma unroll
    for (int nf = 0; nf < 4; ++nf) acc[mf][nf] = (f32x4){0.f, 0.f, 0.f, 0.f};

  const char* xs_raw = reinterpret_cast<const char*>(xs4);

#pragma unroll
  for (int st = 0; st < 18; ++st) {
    const int tap = st >> 1, k21 = st & 1;
    const int kr = tap / 3, kc = tap % 3;
    bf16x8 a[8], bw[4];
#pragma unroll
    for (int mf = 0; mf < 8; ++mf) {
      const int m_loc = wm * 128 + mf * 16 + l15;        // px 0..255
      const int s = ((m_loc >> 4) + kr) * 18 + ((m_loc & 15) + kc);
      const int c = (k21 * 4 + l16) ^ (s & 7);
      a[mf] = *reinterpret_cast<const bf16x8*>(xs_raw + s * 128 + c * 16);
    }
#pragma unroll
    for (int nf = 0; nf < 4; ++nf)
      bw[nf] = *reinterpret_cast<const bf16x8*>(
          wq + ((size_t)((tap * 2 + k21) * 8 + wn * 4 + nf)) * 512 + l * 8);
#pragma unroll
    for (int mf = 0; mf < 8; ++mf)
#pragma unroll
      for (int nf = 0; nf < 4; ++nf)
        acc[mf][nf] = __builtin_amdgcn_mfma_f32_16x16x32_bf16(
            a[mf], bw[nf], acc[mf][nf], 0, 0, 0);
  }

  // ---- epilogue: bias + relu + LDS segment max ----
  float bias[4];
#pragma unroll
  for (int nf = 0; nf < 4; ++nf) bias[nf] = b2[wn * 64 + nf * 16 + l15];

#pragma unroll
  for (int mf = 0; mf < 8; ++mf) {
#pragma unroll
    for (int reg = 0; reg < 4; ++reg) {
      const int m_loc = wm * 128 + mf * 16 + l16 * 4 + reg;   // C/D row (m89)
      const int id = ids_s[m_loc];
#pragma unroll
      for (int nf = 0; nf < 4; ++nf) {
        const int oc = wn * 64 + nf * 16 + l15;               // C/D col
        const float val = fmaxf(acc[mf][nf][reg] + bias[nf], 0.f);
        atomicMax(&smax[id * 132 + oc], __float_as_int(val));
      }
    }
  }
  __syncthreads();

  // ---- drain to per-block partial (uint4, coalesced, no global atomics) ----
  uint4* pb4 = reinterpret_cast<uint4*>(part + ((size_t)b * 16 + blockIdx.x) * (NOBJ * C2));
  const uint4* sm4 = reinterpret_cast<const uint4*>(smax);
#pragma unroll
  for (int i = 0; i < 4; ++i) {
    const int j = t + i * 256;            // < 1024
    const int row = j >> 5, c4 = j & 31;
    pb4[j] = sm4[row * 33 + c4];
  }
}

// ---------------------------------------------------------------------------
// K3: out[b][id][oc] = max over 16 spatial tiles of the per-block partials.
// ---------------------------------------------------------------------------
__global__ __launch_bounds__(256) void k3_reduce(
    const float* __restrict__ part, float* __restrict__ out)
{
  const int idx = blockIdx.x * 256 + threadIdx.x;   // < 32*4096
  const int b = idx >> 12, slot = idx & 4095;
  const float* p = part + (size_t)b * 16 * 4096 + slot;
  float m = 0.f;
#pragma unroll
  for (int tl = 0; tl < 16; ++tl) m = fmaxf(m, p[tl * 4096]);
  out[idx] = m;
}

extern "C" void kernel_launch(void* const* d_in, const int* in_sizes, int n_in,
                              void* d_out, int out_size, void* d_ws, size_t ws_size,
                              hipStream_t stream)
{
  (void)in_sizes; (void)n_in; (void)ws_size; (void)out_size;
  const float* images = (const float*)d_in[0];
  const int*   rois   = (const int*)d_in[1];
  const float* w1     = (const float*)d_in[2];
  const float* b1     = (const float*)d_in[3];
  const float* w2     = (const float*)d_in[4];
  const float* b2     = (const float*)d_in[5];

  // ws: [xpad 17.8MB][wq 147KB][wp1 20KB][part 8.4MB]
  const size_t xpad_bytes = (size_t)32 * PADW * PADW * C1 * 2;
  const size_t wq_bytes   = (size_t)9 * C2 * C1 * 2;   // 147,456 B
  const size_t wp1_bytes  = (size_t)10 * C1 * 16 * 2;

  unsigned short* xpad = (unsigned short*)d_ws;
  unsigned short* wq   = (unsigned short*)((char*)d_ws + xpad_bytes);
  unsigned short* wp1  = (unsigned short*)((char*)d_ws + xpad_bytes + wq_bytes);
  float* part = (float*)((char*)d_ws + xpad_bytes + wq_bytes + wp1_bytes);

  hipLaunchKernelGGL(k0_pack_w1, dim3(40), dim3(256), 0, stream, w1, wp1);

  hipLaunchKernelGGL(k1_mfma, dim3(64, 33), dim3(512), 0, stream,
                     images, wp1, b1, w2, wq, xpad);

  hipLaunchKernelGGL(k2_mfma, dim3(16, 32), dim3(256), 0, stream,
                     xpad, wq, b2, rois, part);

  hipLaunchKernelGGL(k3_reduce, dim3(512), dim3(256), 0, stream,
                     part, (float*)d_out);
}

// Round 21
// 56.262 us; speedup vs baseline: 1.1263x; 1.1263x over previous
//
#include <hip/hip_runtime.h>

#define IN 128
#define PD 64
#define C1 64
#define C2 128
#define ICC 12
#define NOBJ 32
#define PADW 66    // 64 + 1 halo each side (conv2 input)

typedef __attribute__((ext_vector_type(8))) short bf16x8;
typedef __attribute__((ext_vector_type(4))) float f32x4;

static __device__ __forceinline__ unsigned short f2bf(float f) {
  unsigned u = __float_as_uint(f);
  return (unsigned short)((u + 0x7FFFu + ((u >> 16) & 1u)) >> 16);  // RNE
}

// ---------------------------------------------------------------------------
// K0b: pack w1 (64,12,3,3) f32 -> wp1[tap(10)][oc(64)][ch(16)] bf16 (20 KB).
// ---------------------------------------------------------------------------
__global__ __launch_bounds__(256) void k0_pack_w1(
    const float* __restrict__ w1, unsigned short* __restrict__ wp)
{
  int i = blockIdx.x * 256 + threadIdx.x;
  if (i < 10 * C1 * 16) {
    int tap = i >> 10;
    int rem = i & 1023;
    int oc = rem >> 4, ch = rem & 15;
    float v = (tap < 9 && ch < ICC) ? w1[((size_t)oc * ICC + ch) * 9 + tap] : 0.f;
    wp[i] = f2bf(v);
  }
}

// ---------------------------------------------------------------------------
// K1: conv1 via MFMA (16x16x32), batched two-phase staging, fused /255
// conversion, in-register 2x2 maxpool + bias + relu -> xpad bf16 NHWC.
// grid (64, 33); y==32 packs w2 -> wq. (R15 configuration — session best.)
// ---------------------------------------------------------------------------
__global__ __launch_bounds__(512, 4) void k1_mfma(
    const float* __restrict__ img, const unsigned short* __restrict__ wp1,
    const float* __restrict__ b1, const float* __restrict__ w2,
    unsigned short* __restrict__ wq, unsigned short* __restrict__ xpad)
{
  const int t = threadIdx.x;

  if (blockIdx.y == 32) {
    for (int j = blockIdx.x * 512 + t; j < 9 * C2 * C1; j += 64 * 512) {
      const int tmp = j / 9, tap = j - tmp * 9;   // j = (oc*64+ic)*9 + tap
      const int ic = tmp & 63, oc = tmp >> 6;
      const int k2 = ic >> 5, l16 = (ic >> 3) & 3, e = ic & 7;
      const int ocb = oc >> 4, l15 = oc & 15;
      wq[((tap * 2 + k2) * 8 + ocb) * 512 + l16 * 128 + l15 * 8 + e] = f2bf(w2[j]);
    }
    return;
  }

  const int l = t & 63, w = t >> 6;
  const int wm = w >> 1, wn = w & 1;          // 4M x 2N
  const int bx = blockIdx.x & 7, by = blockIdx.x >> 3;
  const int b  = blockIdx.y;
  const int l15 = l & 15, l16 = l >> 4;

  __shared__ uint4 xs4[324 * 3];              // 324 pix x 48B = 15552 B (pad)

  if (t < 324) {
    unsigned int* xu = reinterpret_cast<unsigned int*>(xs4);
    xu[t * 12 + 6] = 0;
    xu[t * 12 + 7] = 0;
  }

  const float* imgb = img + ((size_t)b * ICC << 14);
  float v0[4], v1[4];
  int   dpix[4], dcp[4];
#pragma unroll
  for (int it = 0; it < 4; ++it) {
    const int i = t + it * 512;               // < 1944 = 324 px * 6 cp
    const bool ok = i < 1944;
    const int cp  = ok ? (i / 324) : 0;
    const int pix = i - cp * 324;
    const int y = (pix * 57) >> 10;           // pix / 18
    const int x = pix - y * 18;
    const int iy = by * 16 + y - 1, ix = bx * 16 + x - 1;
    dpix[it] = pix; dcp[it] = cp;
    v0[it] = 0.f; v1[it] = 0.f;
    if (ok && iy >= 0 && iy < IN && ix >= 0 && ix < IN) {
      const float* p0 = imgb + ((size_t)(2 * cp) << 14) + iy * IN + ix;
      v0[it] = p0[0];
      v1[it] = p0[16384];
    }
  }
#pragma unroll
  for (int it = 0; it < 4; ++it) {
    if (t + it * 512 < 1944) {
      unsigned short h0 = f2bf(v0[it] * (1.f / 255.f));
      unsigned short h1 = f2bf(v1[it] * (1.f / 255.f));
      reinterpret_cast<unsigned int*>(xs4)[dpix[it] * 12 + dcp[it]] =
          (unsigned int)h0 | ((unsigned int)h1 << 16);
    }
  }
  __syncthreads();

  f32x4 acc[4][2];
#pragma unroll
  for (int mf = 0; mf < 4; ++mf)
#pragma unroll
    for (int nf = 0; nf < 2; ++nf) acc[mf][nf] = (f32x4){0.f, 0.f, 0.f, 0.f};

  const char* xs_raw = reinterpret_cast<const char*>(xs4);
  const int ck = l16 & 1;
#pragma unroll
  for (int kp = 0; kp < 5; ++kp) {
    const int ta = 2 * kp, tb = 2 * kp + 1;   // tb == 9 on last step (zero W)
    const int tbA = (tb > 8) ? 8 : tb;
    const int dya = ta / 3, dxa = ta % 3;
    const int dyb = tbA / 3, dxb = tbA % 3;
    const int dy = (l16 < 2) ? dya : dyb;
    const int dx = (l16 < 2) ? dxa : dxb;
    const int tw = (l16 < 2) ? ta : tb;       // tap 9 -> zeros in wp1

    bf16x8 a[4], bw[2];
#pragma unroll
    for (int mf = 0; mf < 4; ++mf) {
      const int row = wm * 4 + mf;
      const int s = (row + dy) * 18 + (l15 + dx);
      a[mf] = *reinterpret_cast<const bf16x8*>(xs_raw + s * 48 + ck * 16);
    }
#pragma unroll
    for (int nf = 0; nf < 2; ++nf) {
      const int oc = wn * 32 + nf * 16 + l15;
      bw[nf] = *reinterpret_cast<const bf16x8*>(wp1 + ((tw * C1 + oc) * 16 + ck * 8));
    }
#pragma unroll
    for (int mf = 0; mf < 4; ++mf)
#pragma unroll
      for (int nf = 0; nf < 2; ++nf)
        acc[mf][nf] = __builtin_amdgcn_mfma_f32_16x16x32_bf16(
            a[mf], bw[nf], acc[mf][nf], 0, 0, 0);
  }

  float bias[2];
#pragma unroll
  for (int nf = 0; nf < 2; ++nf) bias[nf] = b1[wn * 32 + nf * 16 + l15];

#pragma unroll
  for (int q = 0; q < 2; ++q) {
    const int gy = by * 8 + wm * 2 + q;       // pooled row
    unsigned short* orow = xpad + (((size_t)b * PADW + (gy + 1)) * PADW + 1) * C1;
#pragma unroll
    for (int nf = 0; nf < 2; ++nf) {
      const int oc = wn * 32 + nf * 16 + l15;
      const f32x4 A0 = acc[2 * q][nf], A1 = acc[2 * q + 1][nf];
      const float p0 = fmaxf(fmaxf(A0[0], A0[1]), fmaxf(A1[0], A1[1]));
      const float p1 = fmaxf(fmaxf(A0[2], A0[3]), fmaxf(A1[2], A1[3]));
      const float v0s = fmaxf(p0 + bias[nf], 0.f);
      const float v1s = fmaxf(p1 + bias[nf], 0.f);
      const int gx0 = bx * 8 + l16 * 2;
      orow[(size_t)gx0 * C1 + oc]       = f2bf(v0s);
      orow[(size_t)(gx0 + 1) * C1 + oc] = f2bf(v1s);
    }
  }
}

// ---------------------------------------------------------------------------
// K2: conv2 implicit GEMM (R15 configuration): 256 thr (4 waves = 2M x 2N),
// 16w x 8h px x 128 oc, 1024 blocks, batched staging, 2-deep register
// pipeline, wave-contiguous wq B loads, LDS segment-max epilogue.
// ---------------------------------------------------------------------------
__global__ __launch_bounds__(256) void k2_mfma(
    const unsigned short* __restrict__ xpad, const unsigned short* __restrict__ wq,
    const float* __restrict__ b2, const int* __restrict__ rois,
    float* __restrict__ part)
{
  const int t  = threadIdx.x;
  const int l  = t & 63, w = t >> 6;
  const int wm = w >> 1, wn = w & 1;
  const int bx = blockIdx.x & 3, by = blockIdx.x >> 2;   // 4 x 8 tiles
  const int b  = blockIdx.y;
  const int l15 = l & 15, l16 = l >> 4;

  __shared__ uint4 xs4[180 * 8];          // 10x18 pixels x 128B = 23 KB
  __shared__ int   smax[NOBJ * 132];      // padded rows of 132 (33 uint4)
  __shared__ int   ids_s[128];

  const unsigned short* xb = xpad + (size_t)b * PADW * PADW * C1;
  uint4 sv[6];
#pragma unroll
  for (int it = 0; it < 6; ++it) {
    const int i = t + it * 256;           // < 1440
    const bool ok = i < 1440;
    const int r = i >> 3, ps = i & 7;
    const int y = (r * 57) >> 10;         // r / 18
    const int x = r - y * 18;
    const int cl = ps ^ (r & 7);
    const int gy = by * 8 + y, gx = bx * 16 + x;
    sv[it] = make_uint4(0, 0, 0, 0);
    if (ok && gy >= 1 && gy <= PD && gx >= 1 && gx <= PD)
      sv[it] = *(reinterpret_cast<const uint4*>(xb + ((size_t)gy * PADW + gx) * C1) + cl);
  }
#pragma unroll
  for (int it = 0; it < 6; ++it)
    if (t + it * 256 < 1440) xs4[t + it * 256] = sv[it];

  if (t < 128) {
    const int py = t >> 4, pxx = t & 15;
    ids_s[t] = rois[((size_t)b * IN + 2 * (by * 8 + py)) * IN + 2 * (bx * 16 + pxx)];
  }
  {
    uint4* sm4 = reinterpret_cast<uint4*>(smax);
    const uint4 z = make_uint4(0, 0, 0, 0);
#pragma unroll
    for (int i = 0; i < 5; ++i) {
      const int j = t + i * 256;
      if (j < 1056) sm4[j] = z;           // 32*132/4 = 1056
    }
  }
  __syncthreads();

  f32x4 acc[4][4];
#pragma unroll
  for (int mf = 0; mf < 4; ++mf)
#pragma unroll
    for (int nf = 0; nf < 4; ++nf) acc[mf][nf] = (f32x4){0.f, 0.f, 0.f, 0.f};

  const char* xs_raw = reinterpret_cast<const char*>(xs4);

  bf16x8 aR[2][4], bR[2][4];
#pragma unroll
  for (int mf = 0; mf < 4; ++mf) {
    const int m_loc = wm * 64 + mf * 16 + l15;
    const int s = (m_loc >> 4) * 18 + (m_loc & 15);     // kr=kc=0
    const int c = l16 ^ (s & 7);
    aR[0][mf] = *reinterpret_cast<const bf16x8*>(xs_raw + s * 128 + c * 16);
  }
#pragma unroll
  for (int nf = 0; nf < 4; ++nf)
    bR[0][nf] = *reinterpret_cast<const bf16x8*>(
        wq + ((size_t)(wn * 4 + nf)) * 512 + l * 8);

#pragma unroll
  for (int st = 0; st < 18; ++st) {
    const int cur = st & 1, nxt = cur ^ 1;
    if (st < 17) {
      const int s1 = st + 1;
      const int tap1 = s1 >> 1, k21 = s1 & 1;
      const int kr1 = tap1 / 3, kc1 = tap1 % 3;
#pragma unroll
      for (int nf = 0; nf < 4; ++nf)
        bR[nxt][nf] = *reinterpret_cast<const bf16x8*>(
            wq + ((size_t)((tap1 * 2 + k21) * 8 + wn * 4 + nf)) * 512 + l * 8);
#pragma unroll
      for (int mf = 0; mf < 4; ++mf) {
        const int m_loc = wm * 64 + mf * 16 + l15;
        const int s = ((m_loc >> 4) + kr1) * 18 + ((m_loc & 15) + kc1);
        const int c = (k21 * 4 + l16) ^ (s & 7);
        aR[nxt][mf] = *reinterpret_cast<const bf16x8*>(xs_raw + s * 128 + c * 16);
      }
    }
#pragma unroll
    for (int mf = 0; mf < 4; ++mf)
#pragma unroll
      for (int nf = 0; nf < 4; ++nf)
        acc[mf][nf] = __builtin_amdgcn_mfma_f32_16x16x32_bf16(
            aR[cur][mf], bR[cur][nf], acc[mf][nf], 0, 0, 0);
  }

  float bias[4];
#pragma unroll
  for (int nf = 0; nf < 4; ++nf) bias[nf] = b2[wn * 64 + nf * 16 + l15];

#pragma unroll
  for (int mf = 0; mf < 4; ++mf) {
#pragma unroll
    for (int reg = 0; reg < 4; ++reg) {
      const int m_loc = wm * 64 + mf * 16 + l16 * 4 + reg;   // C/D row (m89)
      const int id = ids_s[m_loc];
#pragma unroll
      for (int nf = 0; nf < 4; ++nf) {
        const int oc = wn * 64 + nf * 16 + l15;              // C/D col
        const float val = fmaxf(acc[mf][nf][reg] + bias[nf], 0.f);
        atomicMax(&smax[id * 132 + oc], __float_as_int(val));
      }
    }
  }
  __syncthreads();

  uint4* pb4 = reinterpret_cast<uint4*>(part + ((size_t)b * 32 + blockIdx.x) * (NOBJ * C2));
  const uint4* sm4 = reinterpret_cast<const uint4*>(smax);
#pragma unroll
  for (int i = 0; i < 4; ++i) {
    const int j = t + i * 256;            // < 1024
    const int row = j >> 5, c4 = j & 31;
    pb4[j] = sm4[row * 33 + c4];
  }
}

// ---------------------------------------------------------------------------
// K3: out[b][id][oc] = max over 32 spatial tiles of the per-block partials.
// ---------------------------------------------------------------------------
__global__ __launch_bounds__(256) void k3_reduce(
    const float* __restrict__ part, float* __restrict__ out)
{
  const int idx = blockIdx.x * 256 + threadIdx.x;   // < 32*4096
  const int b = idx >> 12, slot = idx & 4095;
  const float* p = part + (size_t)b * 32 * 4096 + slot;
  float m = 0.f;
#pragma unroll
  for (int tl = 0; tl < 32; ++tl) m = fmaxf(m, p[tl * 4096]);
  out[idx] = m;
}

extern "C" void kernel_launch(void* const* d_in, const int* in_sizes, int n_in,
                              void* d_out, int out_size, void* d_ws, size_t ws_size,
                              hipStream_t stream)
{
  (void)in_sizes; (void)n_in; (void)ws_size; (void)out_size;
  const float* images = (const float*)d_in[0];
  const int*   rois   = (const int*)d_in[1];
  const float* w1     = (const float*)d_in[2];
  const float* b1     = (const float*)d_in[3];
  const float* w2     = (const float*)d_in[4];
  const float* b2     = (const float*)d_in[5];

  // ws: [xpad 17.8MB][wq 147KB][wp1 20KB][part 16.8MB]
  const size_t xpad_bytes = (size_t)32 * PADW * PADW * C1 * 2;
  const size_t wq_bytes   = (size_t)9 * C2 * C1 * 2;   // 147,456 B
  const size_t wp1_bytes  = (size_t)10 * C1 * 16 * 2;

  unsigned short* xpad = (unsigned short*)d_ws;
  unsigned short* wq   = (unsigned short*)((char*)d_ws + xpad_bytes);
  unsigned short* wp1  = (unsigned short*)((char*)d_ws + xpad_bytes + wq_bytes);
  float* part = (float*)((char*)d_ws + xpad_bytes + wq_bytes + wp1_bytes);

  hipLaunchKernelGGL(k0_pack_w1, dim3(40), dim3(256), 0, stream, w1, wp1);

  hipLaunchKernelGGL(k1_mfma, dim3(64, 33), dim3(512), 0, stream,
                     images, wp1, b1, w2, wq, xpad);

  hipLaunchKernelGGL(k2_mfma, dim3(32, 32), dim3(256), 0, stream,
                     xpad, wq, b2, rois, part);

  hipLaunchKernelGGL(k3_reduce, dim3(512), dim3(256), 0, stream,
                     part, (float*)d_out);
}